// Round 7
// baseline (49.137 us; speedup 1.0000x reference)
//
#include <hip/hip_runtime.h>
#include <hip/hip_bf16.h>

// B=64, T=2048, D=U=128 (fixed shape)
#define DD 128
#define UU 128
#define SEQ_T 2048
#define ROWS 128
#define PART_STRIDE 132   // per-block partial: [m, l, pad, pad, ctx[128]]

typedef __attribute__((ext_vector_type(8))) short short8;   // 8 bf16
typedef __attribute__((ext_vector_type(4))) float f32x4;    // MFMA C/D

__device__ __forceinline__ unsigned short f2bf(float f) {   // RNE fp32->bf16
  unsigned u = __float_as_uint(f);
  u += 0x7fffu + ((u >> 16) & 1u);
  return (unsigned short)(u >> 16);
}
__device__ __forceinline__ float bf2f(unsigned short s) {
  return __uint_as_float(((unsigned)s) << 16);
}
__device__ __forceinline__ float fast_tanh(float v) {
  float z = __expf(2.0f * v);
  return 1.0f - __fdividef(2.0f, z + 1.0f);
}

// One-shot: Wt[u][d] = bf16(W1[d][u] + W2[d][u]); bias[u] = b1[u]+b2[u]
__global__ void prep_kernel(const float* __restrict__ W1w, const float* __restrict__ W1b,
                            const float* __restrict__ W2w, const float* __restrict__ W2b,
                            unsigned short* __restrict__ wt_g, float* __restrict__ bias_g)
{
  int i = blockIdx.x * 256 + threadIdx.x;   // 16384 = 128*128
  int u = i >> 7, d = i & 127;
  float s = W1w[(size_t)d * UU + u] + W2w[(size_t)d * UU + u];
  wt_g[(size_t)u * DD + d] = f2bf(s);
  if (i < UU) bias_g[i] = W1b[i] + W2b[i];
}

// Fused: 128 rows/block, 4 waves; wave w owns ROWS 32w..32w+31 and ALL 128 u.
// x lives only in registers (bf16 A-fragments, 32 VGPR) -> no x LDS tile, no
// store/reload round-trip; context pass reuses the same registers. Only the
// 32 KB B-matrix (wt) is in LDS (swizzled, r2-verified layout).
__global__ __launch_bounds__(256, 3)
void fused_score_ctx(const float* __restrict__ x,
                     const unsigned short* __restrict__ wt_g,
                     const float* __restrict__ bias_g,
                     const float* __restrict__ Vw,
                     float* __restrict__ part)
{
  __shared__ __align__(16) unsigned short wt[UU * DD];   // 32 KB swizzled bf16
  __shared__ float bsum[UU];
  __shared__ float vv[UU];
  __shared__ float slds[ROWS];
  __shared__ __align__(16) float pctx_red[4][DD];
  __shared__ float red[8];

  const int tid = threadIdx.x;
  const int blk = blockIdx.x;
  const int rowbase = blk * ROWS;
  const int w = tid >> 6, l = tid & 63, lx = l & 15, lq = l >> 4;

  // ---- issue this wave's x loads first (HBM, longest latency) ----
  // lane (lx,lq) needs rows 32w+16mf+lx, d = 32kf+8lq .. +7  (MFMA A layout)
  float4 t0[2][4], t1[2][4];
  #pragma unroll
  for (int mf = 0; mf < 2; ++mf) {
    const float* rsrc = x + (size_t)(rowbase + 32 * w + 16 * mf + lx) * DD + 8 * lq;
    #pragma unroll
    for (int kf = 0; kf < 4; ++kf) {
      t0[mf][kf] = *reinterpret_cast<const float4*>(rsrc + 32 * kf);
      t1[mf][kf] = *reinterpret_cast<const float4*>(rsrc + 32 * kf + 4);
    }
  }

  // ---- stage wt (L2-hit) + bias/V while x loads fly ----
  if (tid < UU) { bsum[tid] = bias_g[tid]; vv[tid] = Vw[tid]; }
  #pragma unroll
  for (int it = 0; it < 8; ++it) {
    int F = tid + 256 * it;
    int u = F >> 4, g = F & 15;
    short8 wv = *reinterpret_cast<const short8*>(wt_g + (size_t)F * 8);
    *reinterpret_cast<short8*>(wt + u * DD + ((g ^ (u & 15)) << 3)) = wv;
  }

  // ---- cvt x -> bf16 A-fragments (in registers, stays for context pass) ----
  short8 Af[2][4];
  #pragma unroll
  for (int mf = 0; mf < 2; ++mf)
    #pragma unroll
    for (int kf = 0; kf < 4; ++kf) {
      float4 v0 = t0[mf][kf], v1 = t1[mf][kf];
      short8 pk;
      pk[0] = (short)f2bf(v0.x); pk[1] = (short)f2bf(v0.y);
      pk[2] = (short)f2bf(v0.z); pk[3] = (short)f2bf(v0.w);
      pk[4] = (short)f2bf(v1.x); pk[5] = (short)f2bf(v1.y);
      pk[6] = (short)f2bf(v1.z); pk[7] = (short)f2bf(v1.w);
      Af[mf][kf] = pk;
    }
  __syncthreads();   // wt, bsum, vv visible

  // ---- GEMM: rows 32w..+31 x all 128 u; A from regs, B from LDS ----
  f32x4 acc[2][8];
  #pragma unroll
  for (int mf = 0; mf < 2; ++mf)
    #pragma unroll
    for (int nf = 0; nf < 8; ++nf) acc[mf][nf] = (f32x4){0.f, 0.f, 0.f, 0.f};
  #pragma unroll
  for (int kf = 0; kf < 4; ++kf) {
    const int gs8 = ((4 * kf + lq) ^ lx) << 3;   // swizzle key = u&15 = lx
    #pragma unroll
    for (int nf = 0; nf < 8; ++nf) {
      short8 b = *reinterpret_cast<const short8*>(wt + (nf * 16 + lx) * DD + gs8);
      acc[0][nf] = __builtin_amdgcn_mfma_f32_16x16x32_bf16(Af[0][kf], b, acc[0][nf], 0, 0, 0);
      acc[1][nf] = __builtin_amdgcn_mfma_f32_16x16x32_bf16(Af[1][kf], b, acc[1][nf], 0, 0, 0);
    }
  }

  // ---- scores (wave-local, no cross-wave reduce: wave owns all u) ----
  float vsr[8], bsr[8];
  #pragma unroll
  for (int nf = 0; nf < 8; ++nf) { vsr[nf] = vv[16 * nf + lx]; bsr[nf] = bsum[16 * nf + lx]; }
  #pragma unroll
  for (int mf = 0; mf < 2; ++mf) {
    #pragma unroll
    for (int r = 0; r < 4; ++r) {
      float p = 0.0f;
      #pragma unroll
      for (int nf = 0; nf < 8; ++nf)
        p += vsr[nf] * fast_tanh(acc[mf][nf][r] + bsr[nf]);
      p += __shfl_xor(p, 1);
      p += __shfl_xor(p, 2);
      p += __shfl_xor(p, 4);
      p += __shfl_xor(p, 8);
      if (lx == 0) slds[32 * w + 16 * mf + 4 * lq + r] = p;  // C row = 4lq+r
    }
  }
  __syncthreads();

  // ---- block softmax stats over 128 rows ----
  float sv = slds[tid & 127];
  float m = sv;
  #pragma unroll
  for (int off = 1; off < 64; off <<= 1) m = fmaxf(m, __shfl_xor(m, off));
  if (l == 0) red[w] = m;
  __syncthreads();
  m = fmaxf(fmaxf(red[0], red[1]), fmaxf(red[2], red[3]));

  float e = (tid < 128) ? __expf(sv - m) : 0.0f;   // each row counted once
  float lsum = e;
  #pragma unroll
  for (int off = 1; off < 64; off <<= 1) lsum += __shfl_xor(lsum, off);
  if (l == 0) red[4 + w] = lsum;
  __syncthreads();
  lsum = (red[4] + red[5]) + (red[6] + red[7]);

  if (tid < 128) slds[tid] = e;
  __syncthreads();

  // ---- context from register-resident Af (no LDS x reads) ----
  {
    float wg0 = slds[32 * w + lx];        // weight for row of mf=0
    float wg1 = slds[32 * w + 16 + lx];   // weight for row of mf=1
    float ca[4][8];
    #pragma unroll
    for (int kf = 0; kf < 4; ++kf)
      #pragma unroll
      for (int e2 = 0; e2 < 8; ++e2)
        ca[kf][e2] = wg0 * bf2f((unsigned short)Af[0][kf][e2])
                   + wg1 * bf2f((unsigned short)Af[1][kf][e2]);
    // reduce over the 16 lx lanes -> full sum over this wave's 32 rows
    #pragma unroll
    for (int kf = 0; kf < 4; ++kf)
      #pragma unroll
      for (int e2 = 0; e2 < 8; ++e2) {
        ca[kf][e2] += __shfl_xor(ca[kf][e2], 1);
        ca[kf][e2] += __shfl_xor(ca[kf][e2], 2);
        ca[kf][e2] += __shfl_xor(ca[kf][e2], 4);
        ca[kf][e2] += __shfl_xor(ca[kf][e2], 8);
      }
    if (lx == 0) {   // 4 lanes (lq) cover d = 32kf+8lq+e
      #pragma unroll
      for (int kf = 0; kf < 4; ++kf) {
        f32x4 lo = (f32x4){ca[kf][0], ca[kf][1], ca[kf][2], ca[kf][3]};
        f32x4 hi = (f32x4){ca[kf][4], ca[kf][5], ca[kf][6], ca[kf][7]};
        *reinterpret_cast<f32x4*>(&pctx_red[w][32 * kf + 8 * lq]) = lo;
        *reinterpret_cast<f32x4*>(&pctx_red[w][32 * kf + 8 * lq + 4]) = hi;
      }
    }
  }
  __syncthreads();

  float* prec = part + (size_t)blk * PART_STRIDE;
  if (tid < 128) {
    float c0 = (pctx_red[0][tid] + pctx_red[1][tid]) +
               (pctx_red[2][tid] + pctx_red[3][tid]);
    prec[4 + tid] = c0;
  }
  if (tid == 0) { prec[0] = m; prec[1] = lsum; }
}

// Flash-style combine of 16 per-block partials per batch row.
__global__ void combine_kernel(const float* __restrict__ part,
                               float* __restrict__ out, int chunks)
{
  int b = blockIdx.x;
  int d = threadIdx.x;  // 128
  float mg = -3.0e38f;
  for (int i = 0; i < chunks; ++i)
    mg = fmaxf(mg, part[(size_t)(b * chunks + i) * PART_STRIDE]);
  float den = 0.0f, num = 0.0f;
  for (int i = 0; i < chunks; ++i) {
    const float* p = part + (size_t)(b * chunks + i) * PART_STRIDE;
    float sc = __expf(p[0] - mg);
    den = fmaf(sc, p[1], den);
    num = fmaf(sc, p[4 + d], num);
  }
  out[(size_t)b * DD + d] = __fdividef(num, den);
}

extern "C" void kernel_launch(void* const* d_in, const int* in_sizes, int n_in,
                              void* d_out, int out_size, void* d_ws, size_t ws_size,
                              hipStream_t stream)
{
  const float* x   = (const float*)d_in[0];
  const float* W1w = (const float*)d_in[1];
  const float* W1b = (const float*)d_in[2];
  const float* W2w = (const float*)d_in[3];
  const float* W2b = (const float*)d_in[4];
  const float* Vw  = (const float*)d_in[5];
  // d_in[6] = V_b: constant on scores, cancels in softmax.

  const int bt = in_sizes[0] / DD;   // 131072
  const int nblk = bt / ROWS;        // 1024
  const int B = bt / SEQ_T;          // 64
  const int chunks = SEQ_T / ROWS;   // 16

  float* part = (float*)d_ws;                                        // 540672 B
  unsigned short* wt_g = (unsigned short*)((char*)d_ws + 540672);    // 32768 B
  float* bias_g = (float*)((char*)d_ws + 540672 + 32768);            // 512 B

  prep_kernel<<<64, 256, 0, stream>>>(W1w, W1b, W2w, W2b, wt_g, bias_g);
  fused_score_ctx<<<nblk, 256, 0, stream>>>(x, wt_g, bias_g, Vw, part);
  combine_kernel<<<B, 128, 0, stream>>>(part, (float*)d_out, chunks);
}

// Round 8
// 44.158 us; speedup vs baseline: 1.1128x; 1.1128x over previous
//
#include <hip/hip_runtime.h>
#include <hip/hip_bf16.h>

// B=64, T=2048, D=U=128 (fixed shape)
#define DD 128
#define UU 128
#define SEQ_T 2048
#define ROWS 64           // rows per block (halved: occupancy + phase stagger)
#define PART_STRIDE 132   // per-block partial: [m, l, pad, pad, ctx[128]]

typedef __attribute__((ext_vector_type(8))) short short8;   // 8 bf16
typedef __attribute__((ext_vector_type(4))) float f32x4;    // MFMA C/D

__device__ __forceinline__ unsigned short f2bf(float f) {   // RNE fp32->bf16
  unsigned u = __float_as_uint(f);
  u += 0x7fffu + ((u >> 16) & 1u);
  return (unsigned short)(u >> 16);
}
__device__ __forceinline__ float bf2f(unsigned short s) {
  return __uint_as_float(((unsigned)s) << 16);
}
__device__ __forceinline__ float fast_tanh(float v) {
  float z = __expf(2.0f * v);
  return 1.0f - __fdividef(2.0f, z + 1.0f);
}

// One-shot: Wt[u][d] = bf16(W1[d][u] + W2[d][u]); bias[u] = b1[u]+b2[u]
__global__ void prep_kernel(const float* __restrict__ W1w, const float* __restrict__ W1b,
                            const float* __restrict__ W2w, const float* __restrict__ W2b,
                            unsigned short* __restrict__ wt_g, float* __restrict__ bias_g)
{
  int i = blockIdx.x * 256 + threadIdx.x;   // 16384 = 128*128
  int u = i >> 7, d = i & 127;
  float s = W1w[(size_t)d * UU + u] + W2w[(size_t)d * UU + u];
  wt_g[(size_t)u * DD + d] = f2bf(s);
  if (i < UU) bias_g[i] = W1b[i] + W2b[i];
}

// Fused: 64 rows/block, 2048 blocks, 4 waves (wave w owns u in [32w,32w+32)).
// x staged bf16 in 16 KB swizzled LDS; B in 32 VGPRs (loaded once, L2-hit).
// ~20 KB LDS + <=128 VGPR -> 4 blocks/CU: staggered blocks mix HBM-stage and
// compute phases across the CU (fixes grid-wide phase lockstep).
__global__ __launch_bounds__(256, 4)
void fused_score_ctx(const float* __restrict__ x,
                     const unsigned short* __restrict__ wt_g,
                     const float* __restrict__ bias_g,
                     const float* __restrict__ Vw,
                     float* __restrict__ part)
{
  __shared__ __align__(16) unsigned short xs[ROWS * DD];  // 16 KB swizzled bf16
  __shared__ __align__(16) float spart[4][ROWS];          // per-wave score partials
  __shared__ float slds[ROWS];
  __shared__ __align__(16) float pctx_red[4][DD];

  const int tid = threadIdx.x;
  const int blk = blockIdx.x;
  const int rowbase = blk * ROWS;
  const int w = tid >> 6, l = tid & 63, lx = l & 15, lq = l >> 4;

  // ---- stage x: issue HBM loads first (longest latency) ----
  float4 xr[8];
  #pragma unroll
  for (int it = 0; it < 4; ++it) {
    int F = tid + 256 * it;            // 1024 granules of 8 elems
    int row = F >> 4, g = F & 15;
    const float* src = x + (size_t)(rowbase + row) * DD + g * 8;
    xr[2 * it]     = *reinterpret_cast<const float4*>(src);
    xr[2 * it + 1] = *reinterpret_cast<const float4*>(src + 4);
  }

  // ---- B fragments + V/bias for this wave's 32 u-columns (L2-hit) ----
  short8 Bf[2][4];
  float vs[2], bs[2];
  #pragma unroll
  for (int nf = 0; nf < 2; ++nf) {
    const int u = 32 * w + 16 * nf + lx;
    vs[nf] = Vw[u];
    bs[nf] = bias_g[u];
    #pragma unroll
    for (int kf = 0; kf < 4; ++kf)
      Bf[nf][kf] = *reinterpret_cast<const short8*>(
          wt_g + (size_t)u * DD + 32 * kf + 8 * lq);
  }

  // ---- cvt + swizzled LDS write ----
  #pragma unroll
  for (int it = 0; it < 4; ++it) {
    int F = tid + 256 * it;
    int row = F >> 4, g = F & 15;
    float4 v0 = xr[2 * it], v1 = xr[2 * it + 1];
    short8 pk;
    pk[0] = (short)f2bf(v0.x); pk[1] = (short)f2bf(v0.y);
    pk[2] = (short)f2bf(v0.z); pk[3] = (short)f2bf(v0.w);
    pk[4] = (short)f2bf(v1.x); pk[5] = (short)f2bf(v1.y);
    pk[6] = (short)f2bf(v1.z); pk[7] = (short)f2bf(v1.w);
    *reinterpret_cast<short8*>(xs + row * DD + ((g ^ (row & 15)) << 3)) = pk;
  }
  __syncthreads();

  // ---- GEMM: 64 rows x wave's 32 u; A from LDS, B from regs ----
  f32x4 acc[4][2];
  #pragma unroll
  for (int mf = 0; mf < 4; ++mf) {
    acc[mf][0] = (f32x4){0.f, 0.f, 0.f, 0.f};
    acc[mf][1] = (f32x4){0.f, 0.f, 0.f, 0.f};
  }
  #pragma unroll
  for (int kf = 0; kf < 4; ++kf) {
    const int gs8 = ((4 * kf + lq) ^ lx) << 3;   // swizzle key: row&15 == lx
    #pragma unroll
    for (int mf = 0; mf < 4; ++mf) {
      short8 a = *reinterpret_cast<const short8*>(xs + (16 * mf + lx) * DD + gs8);
      acc[mf][0] = __builtin_amdgcn_mfma_f32_16x16x32_bf16(a, Bf[0][kf], acc[mf][0], 0, 0, 0);
      acc[mf][1] = __builtin_amdgcn_mfma_f32_16x16x32_bf16(a, Bf[1][kf], acc[mf][1], 0, 0, 0);
    }
  }

  // ---- per-wave score partials over this wave's u ----
  #pragma unroll
  for (int mf = 0; mf < 4; ++mf) {
    #pragma unroll
    for (int r = 0; r < 4; ++r) {
      float p = vs[0] * fast_tanh(acc[mf][0][r] + bs[0])
              + vs[1] * fast_tanh(acc[mf][1][r] + bs[1]);
      p += __shfl_xor(p, 1);
      p += __shfl_xor(p, 2);
      p += __shfl_xor(p, 4);
      p += __shfl_xor(p, 8);
      if (lx == 0) spart[w][16 * mf + 4 * lq + r] = p;   // C/D row = 4lq+r
    }
  }
  __syncthreads();

  // ---- softmax stats: row = lane (each wave holds all 64 rows) ----
  float sv = (spart[0][l] + spart[1][l]) + (spart[2][l] + spart[3][l]);
  float m = sv;
  #pragma unroll
  for (int off = 1; off < 64; off <<= 1) m = fmaxf(m, __shfl_xor(m, off));
  float e = __expf(sv - m);
  float lsum = e;
  #pragma unroll
  for (int off = 1; off < 64; off <<= 1) lsum += __shfl_xor(lsum, off);
  if (w == 0) slds[l] = e;     // one wave publishes weights
  __syncthreads();

  // ---- partial context: thread = (t-group of 4 rows, d-granule) ----
  {
    const int gd = tid & 15;          // d-granule (8 d's)
    const int tg = tid >> 4;          // 16 groups of 4 rows
    float ca[8];
    #pragma unroll
    for (int e2 = 0; e2 < 8; ++e2) ca[e2] = 0.0f;
    #pragma unroll
    for (int k = 0; k < 4; ++k) {
      int t = tg * 4 + k;
      float wgt = slds[t];
      short8 xv = *reinterpret_cast<const short8*>(xs + t * DD + ((gd ^ (t & 15)) << 3));
      #pragma unroll
      for (int e2 = 0; e2 < 8; ++e2)
        ca[e2] = fmaf(wgt, bf2f((unsigned short)xv[e2]), ca[e2]);
    }
    #pragma unroll
    for (int e2 = 0; e2 < 8; ++e2) {
      ca[e2] += __shfl_xor(ca[e2], 16);
      ca[e2] += __shfl_xor(ca[e2], 32);
    }
    if ((l >> 4) == 0) {              // lanes 0..15: gd == l
      #pragma unroll
      for (int e2 = 0; e2 < 8; ++e2) pctx_red[w][gd * 8 + e2] = ca[e2];
    }
  }
  __syncthreads();

  float* prec = part + (size_t)blk * PART_STRIDE;
  if (tid < 128) {
    float c0 = (pctx_red[0][tid] + pctx_red[1][tid]) +
               (pctx_red[2][tid] + pctx_red[3][tid]);
    prec[4 + tid] = c0;
  }
  if (tid == 0) { prec[0] = m; prec[1] = lsum; }
}

// Flash-style combine of 32 per-block partials per batch row.
__global__ void combine_kernel(const float* __restrict__ part,
                               float* __restrict__ out, int chunks)
{
  int b = blockIdx.x;
  int d = threadIdx.x;  // 128
  float mg = -3.0e38f;
  for (int i = 0; i < chunks; ++i)
    mg = fmaxf(mg, part[(size_t)(b * chunks + i) * PART_STRIDE]);
  float den = 0.0f, num = 0.0f;
  for (int i = 0; i < chunks; ++i) {
    const float* p = part + (size_t)(b * chunks + i) * PART_STRIDE;
    float sc = __expf(p[0] - mg);
    den = fmaf(sc, p[1], den);
    num = fmaf(sc, p[4 + d], num);
  }
  out[(size_t)b * DD + d] = __fdividef(num, den);
}

extern "C" void kernel_launch(void* const* d_in, const int* in_sizes, int n_in,
                              void* d_out, int out_size, void* d_ws, size_t ws_size,
                              hipStream_t stream)
{
  const float* x   = (const float*)d_in[0];
  const float* W1w = (const float*)d_in[1];
  const float* W1b = (const float*)d_in[2];
  const float* W2w = (const float*)d_in[3];
  const float* W2b = (const float*)d_in[4];
  const float* Vw  = (const float*)d_in[5];
  // d_in[6] = V_b: constant on scores, cancels in softmax.

  const int bt = in_sizes[0] / DD;   // 131072
  const int nblk = bt / ROWS;        // 2048
  const int B = bt / SEQ_T;          // 64
  const int chunks = SEQ_T / ROWS;   // 32

  const size_t part_bytes = (size_t)nblk * PART_STRIDE * sizeof(float);  // ~1.08 MB
  float* part = (float*)d_ws;
  unsigned short* wt_g = (unsigned short*)((char*)d_ws + part_bytes);
  float* bias_g = (float*)((char*)d_ws + part_bytes + 32768);

  prep_kernel<<<64, 256, 0, stream>>>(W1w, W1b, W2w, W2b, wt_g, bias_g);
  fused_score_ctx<<<nblk, 256, 0, stream>>>(x, wt_g, bias_g, Vw, part);
  combine_kernel<<<B, 128, 0, stream>>>(part, (float*)d_out, chunks);
}